// Round 9
// baseline (82.088 us; speedup 1.0000x reference)
//
#include <hip/hip_runtime.h>

// Quantized 3x3 conv, stride 1, pad 1 (pad value = input zero point 3).
// x: int32 [32][128][56][56] (values in int8 range)
// weight: int32 [256][128][3][3]
// bias: int32 [256]
// weight_scale: float [256]
// out: int32 [32][256][56][56] (quantized int8 values in int32 container)

#define NB    32
#define CIN   128
#define HH    56
#define WW    56
#define COUT  256
#define PIX   (HH*WW)     // 3136
#define KTOT  1152        // 9 * 128
#define NCHUNK 18         // K chunks of 64

#define NPT   28          // pixel tiles per batch (3136 = 28*112)
#define BN    112         // pixels per block = 2 output rows x 56
#define NJ    7           // B fragments per wave (112/16)
#define IMGC  58          // image cols (input cols -1..56 shifted by +1)
#define IMGB  (4*IMGC*128)  // LDS image: 4 rows x 58 cols x 128 ci = 29696 B

typedef int v4i __attribute__((ext_vector_type(4)));

// ---------------- Phase 1: pack weight into FRAGMENT order ----------------
// w8f[((t*16 + g)*16 + lr)*64 + (k&63)], t=k>>6 chunk, g=co>>4, lr=co&15,
// k = r*128 + ci (tap-major). A wave's A-fragment = contiguous 1KB.
__global__ void pack_w_kernel(const int* __restrict__ wt,
                              unsigned char* __restrict__ w8f) {
    int co = blockIdx.x;           // 256
    int t  = threadIdx.x;          // 128
    for (int idx = t; idx < KTOT/4; idx += 128) {
        int k  = idx * 4;
        int r  = k >> 7;           // tap 0..8
        int ci = k & 127;
        const int* wb = wt + ((co*CIN + ci)*9 + r);
        int v0 = wb[0], v1 = wb[9], v2 = wb[18], v3 = wb[27];
        unsigned int pack = (v0 & 0xFF) | ((v1 & 0xFF) << 8) |
                            ((v2 & 0xFF) << 16) | ((unsigned)(v3 & 0xFF) << 24);
        int tch = k >> 6;
        size_t dst = ((size_t)((tch*16 + (co >> 4))*16 + (co & 15)))*64 + (k & 63);
        *(unsigned int*)(w8f + dst) = pack;
    }
}

// ---------------- Phase 2: fused pack + implicit GEMM ---------------------
// Grid: 28 tiles * 32 batches = 896 blocks, 256 threads = 4 waves.
// Tile: 256 co x 112 px (output rows 2pt, 2pt+1).
// Pack phase: input rows h0-1..h0+2 (zero-point padded) -> LDS image
//   [4][58][128] int8, XOR-swizzled (byte ^= ((px&7)<<4), px = byte>>7)
//   so K-loop ds_read_b128 at px-stride 128B is ~2-way (free).
// K-loop (barrier-free, image is read-only after one __syncthreads):
//   A: fragment-ordered w8f -> regs, coalesced 1KB loads, double-buffered.
//   B: 7 swizzled ds_read_b128 from the image per chunk. 28 MFMA per wave.
__launch_bounds__(256, 2)
__global__ void conv_kernel(const unsigned char* __restrict__ w8f,
                            const int* __restrict__ x,
                            const int* __restrict__ bias,
                            const float* __restrict__ wscale,
                            int* __restrict__ out) {
    __shared__ __align__(16) unsigned char img[IMGB];

    int bx = blockIdx.x;
    int pt = bx % NPT;
    int nb = bx / NPT;
    int h0 = pt * 2;               // first output row
    int p0 = pt * BN;

    int tid  = threadIdx.x;
    int lane = tid & 63;
    int wm   = tid >> 6;           // 0..3
    int lr   = lane & 15;
    int lg   = lane >> 4;

    // ================= pack phase =================
    {
        int wl = lane;             // col 0..55 active
        int cg = wm;               // ci phase
        const int s = HH*WW;
#pragma unroll
        for (int hh = 0; hh < 4; ++hh) {
            int hi = h0 - 1 + hh;
            unsigned int* rowl = (unsigned int*)&img[hh*IMGC*128];
            if (hi < 0 || hi >= HH) {
                for (int i = tid; i < IMGC*32; i += 256)
                    rowl[i] = 0x03030303u;      // pad row (constant: swizzle moot)
            } else {
                if (tid < 64) {                  // border cols ic=0, ic=57
                    int off = (tid < 32) ? tid : (57*32 + (tid - 32));
                    rowl[off] = 0x03030303u;
                }
                if (wl < WW) {
#pragma unroll
                    for (int k = 0; k < 8; ++k) {
                        int ci0 = cg*4 + k*16;
                        const int* xb = x + (((size_t)(nb*CIN + ci0)*HH + hi)*WW + wl);
                        int v0 = xb[0], v1 = xb[s], v2 = xb[2*s], v3 = xb[3*s];
                        unsigned int pack = (v0 & 0xFF) | ((v1 & 0xFF) << 8) |
                                            ((v2 & 0xFF) << 16) |
                                            ((unsigned)(v3 & 0xFF) << 24);
                        int waddr = ((hh*IMGC + wl + 1) << 7) + ci0;
                        waddr ^= ((waddr >> 7) & 7) << 4;   // match read swizzle
                        *(unsigned int*)&img[waddr] = pack;
                    }
                }
            }
        }
    }
    __syncthreads();               // image complete; read-only below

    // ================= GEMM phase =================
    // per-lane fragment pre-offsets: p = j*16+lr -> (r,c); pre = (r*58+c)*128
    int pre[NJ];
#pragma unroll
    for (int j = 0; j < NJ; ++j) {
        int p = j*16 + lr;
        int r = (p >= 56) ? 1 : 0;
        int c = p - 56*r;
        pre[j] = (r*IMGC + c) << 7;
    }

    const unsigned char* abase = w8f + (size_t)(wm*4)*1024 + (lr*64 + lg*16);

    v4i acc[4][NJ];
#pragma unroll
    for (int i = 0; i < 4; ++i)
#pragma unroll
        for (int j = 0; j < NJ; ++j)
            acc[i][j] = (v4i){0, 0, 0, 0};

    v4i a_cur[4], a_nxt[4];
#pragma unroll
    for (int i = 0; i < 4; ++i) a_cur[i] = *(const v4i*)(abase + i*1024);

#pragma unroll
    for (int t = 0; t < NCHUNK; ++t) {
        if (t < NCHUNK-1) {
#pragma unroll
            for (int i = 0; i < 4; ++i)
                a_nxt[i] = *(const v4i*)(abase + (size_t)(t+1)*16384 + i*1024);
        }
        int r  = t >> 1;
        int kh = (r >= 6) ? 2 : (r >= 3 ? 1 : 0);
        int kw = r - kh*3;
        int uoff = ((kh*IMGC + kw) << 7) + ((t & 1) << 6) + lg*16;

        v4i b_[NJ];
#pragma unroll
        for (int j = 0; j < NJ; ++j) {
            int ba = pre[j] + uoff;
            ba ^= ((ba >> 7) & 7) << 4;
            b_[j] = *(const v4i*)&img[ba];
        }
#pragma unroll
        for (int i = 0; i < 4; ++i)
#pragma unroll
            for (int j = 0; j < NJ; ++j)
                acc[i][j] = __builtin_amdgcn_mfma_i32_16x16x64_i8(
                    a_cur[i], b_[j], acc[i][j], 0, 0, 0);
        if (t < NCHUNK-1) {
#pragma unroll
            for (int i = 0; i < 4; ++i) a_cur[i] = a_nxt[i];
        }
    }

    // Epilogue: q = clamp(rint((acc+bias) * (0.05*ws/0.1) + (-2)), -128, 127)
#pragma unroll
    for (int i = 0; i < 4; ++i) {
#pragma unroll
        for (int rr = 0; rr < 4; ++rr) {
            int co = wm*64 + i*16 + lg*4 + rr;
            float sc = __fdiv_rn(__fmul_rn(0.05f, wscale[co]), 0.1f);
            int bs = bias[co];
            int* orow = out + ((size_t)(nb*COUT + co))*PIX + p0;
#pragma unroll
            for (int j = 0; j < NJ; ++j) {
                float accf = (float)(acc[i][j][rr] + bs);
                float y = __fadd_rn(__fmul_rn(accf, sc), -2.0f);
                y = rintf(y);
                y = fminf(fmaxf(y, -128.0f), 127.0f);
                orow[j*16 + lr] = (int)y;
            }
        }
    }
}

// ---------------- Fallback: naive direct conv (only if ws too small) ------
__launch_bounds__(256)
__global__ void conv_direct_kernel(const int* __restrict__ x,
                                   const int* __restrict__ wt,
                                   const int* __restrict__ bias,
                                   const float* __restrict__ wscale,
                                   int* __restrict__ out) {
    size_t idx = (size_t)blockIdx.x * 256 + threadIdx.x;
    if (idx >= (size_t)NB * COUT * PIX) return;
    int w  = idx % WW;
    int h  = (idx / WW) % HH;
    int co = (idx / PIX) % COUT;
    int nb = idx / ((size_t)PIX * COUT);
    int acc = 0;
    for (int ci = 0; ci < CIN; ++ci) {
        const int* xb = x + ((size_t)(nb*CIN + ci)*HH)*WW;
        const int* wb = wt + ((size_t)(co*CIN + ci)*9);
        for (int kh = 0; kh < 3; ++kh) {
            int hh = h + kh - 1;
            for (int kw = 0; kw < 3; ++kw) {
                int ww2 = w + kw - 1;
                int xv = (hh >= 0 && hh < HH && ww2 >= 0 && ww2 < WW)
                         ? xb[hh*WW + ww2] : 3;
                acc += xv * wb[kh*3 + kw];
            }
        }
    }
    float sc = __fdiv_rn(__fmul_rn(0.05f, wscale[co]), 0.1f);
    float y = __fadd_rn(__fmul_rn((float)(acc + bias[co]), sc), -2.0f);
    y = rintf(y);
    y = fminf(fmaxf(y, -128.0f), 127.0f);
    out[idx] = (int)y;
}

extern "C" void kernel_launch(void* const* d_in, const int* in_sizes, int n_in,
                              void* d_out, int out_size, void* d_ws, size_t ws_size,
                              hipStream_t stream) {
    const int*   x      = (const int*)d_in[0];
    const int*   weight = (const int*)d_in[1];
    const int*   bias   = (const int*)d_in[2];
    const float* wscale = (const float*)d_in[3];
    int*         out    = (int*)d_out;

    if (ws_size < 294912) {        // need 288KB for w8f
        size_t total = (size_t)NB * COUT * PIX;
        conv_direct_kernel<<<dim3((total + 255) / 256), dim3(256), 0, stream>>>(
            x, weight, bias, wscale, out);
        return;
    }

    unsigned char* w8f = (unsigned char*)d_ws;
    pack_w_kernel<<<dim3(COUT), dim3(128), 0, stream>>>(weight, w8f);
    conv_kernel<<<dim3(NPT*NB), dim3(256), 0, stream>>>(w8f, x, bias, wscale, out);
}

// Round 10
// 63.586 us; speedup vs baseline: 1.2910x; 1.2910x over previous
//
#include <hip/hip_runtime.h>

// Quantized 3x3 conv, stride 1, pad 1 (pad value = input zero point 3).
// x: int32 [32][128][56][56] (values in int8 range)
// weight: int32 [256][128][3][3]
// bias: int32 [256]
// weight_scale: float [256]
// out: int32 [32][256][56][56] (quantized int8 values in int32 container)

#define NB    32
#define CIN   128
#define HH    56
#define WW    56
#define COUT  256
#define HP    58          // padded H
#define WP    58          // padded W
#define PIX   (HH*WW)     // 3136
#define KTOT  1152        // 9 * 128
#define NCHUNK 18         // K chunks of 64
#define NPHASE 9          // 2 chunks per phase

#define NPT   28          // pixel tiles per batch (3136 = 28*112)
#define BN    112         // pixels per block
#define NJ    7           // B fragments per wave (112/16)
#define CHB   (NJ*1024)   // one chunk of B in LDS: 7168 B
#define PHB   (2*CHB)     // one phase (2 chunks): 14336 B; ring of 3

typedef int v4i __attribute__((ext_vector_type(4)));

#define GLOAD_LDS(gsrc, ldst) \
    __builtin_amdgcn_global_load_lds( \
        (const __attribute__((address_space(1))) void*)(gsrc), \
        (__attribute__((address_space(3))) void*)(ldst), 16, 0, 0)

// ---------------- Phase 1a: pack x (NCHW int32 -> padded NHWC int8) -------
// LDS-transpose: coalesced global reads (lanes = w) AND coalesced global
// writes (lanes = contiguous dwords). LDS u32 tile [56][33] (2-way alias,
// free). Borders filled inline; all threads reach the barrier.
__global__ void pack_x_kernel(const int* __restrict__ x,
                              unsigned char* __restrict__ xp8,
                              int n0) {
    int bx = blockIdx.x;
    int nl = bx / HP;
    int hp = bx % HP;
    int nb = n0 + nl;
    int tid = threadIdx.x;         // 256
    unsigned int* rowo = (unsigned int*)(xp8 + (size_t)(nl*HP + hp) * WP * CIN);

    if (hp == 0 || hp == HP-1) {   // full pad row: 1856 dwords
        const v4i zp = {0x03030303, 0x03030303, 0x03030303, 0x03030303};
        for (int i = tid; i < (WP*CIN)/16; i += 256)
            ((v4i*)rowo)[i] = zp;
        return;
    }

    __shared__ unsigned int lt[WW * 33];   // 56 x 33 dwords = 7392 B

    int h  = hp - 1;
    int wl = tid & 63;             // lane = w (0..55 active)
    int cg = tid >> 6;             // wave index = ci phase 0..3
    if (wl < WW) {
        const int s = HH*WW;
#pragma unroll
        for (int k = 0; k < 8; ++k) {
            int ci0 = cg*4 + k*16;
            const int* xb = x + (((size_t)(nb*CIN + ci0)*HH + h)*WW + wl);
            int v0 = xb[0], v1 = xb[s], v2 = xb[2*s], v3 = xb[3*s];
            unsigned int pack = (v0 & 0xFF) | ((v1 & 0xFF) << 8) |
                                ((v2 & 0xFF) << 16) | ((unsigned)(v3 & 0xFF) << 24);
            lt[wl*33 + (ci0 >> 2)] = pack;
        }
    }
    __syncthreads();

#pragma unroll
    for (int it = 0; it < 7; ++it) {
        int idx = it*256 + tid;
        int p = idx >> 5;          // pixel 0..55
        int d = idx & 31;          // dword within pixel
        rowo[(p + 1)*32 + d] = lt[p*33 + d];
    }
    if (tid < 64) {
        int off = (tid < 32) ? tid : ((WP-1)*32 + (tid - 32));
        rowo[off] = 0x03030303u;
    }
}

// ---------------- Phase 1b: pack weight into FRAGMENT order ----------------
// w8f[((t*16 + g)*16 + lr)*64 + (k&63)], t=k>>6 chunk, g=co>>4, lr=co&15,
// k = r*128 + ci (tap-major). A wave's A-fragment = contiguous 1KB.
__global__ void pack_w_kernel(const int* __restrict__ wt,
                              unsigned char* __restrict__ w8f) {
    int co = blockIdx.x;           // 256
    int t  = threadIdx.x;          // 128
    for (int idx = t; idx < KTOT/4; idx += 128) {
        int k  = idx * 4;
        int r  = k >> 7;           // tap 0..8
        int ci = k & 127;
        const int* wb = wt + ((co*CIN + ci)*9 + r);
        int v0 = wb[0], v1 = wb[9], v2 = wb[18], v3 = wb[27];
        unsigned int pack = (v0 & 0xFF) | ((v1 & 0xFF) << 8) |
                            ((v2 & 0xFF) << 16) | ((unsigned)(v3 & 0xFF) << 24);
        int tch = k >> 6;
        size_t dst = ((size_t)((tch*16 + (co >> 4))*16 + (co & 15)))*64 + (k & 63);
        *(unsigned int*)(w8f + dst) = pack;
    }
}

__device__ __forceinline__ int koff_of(int t) {
    int r  = t >> 1;
    int kh = (r >= 6) ? 2 : (r >= 3 ? 1 : 0);
    int kw = r - kh*3;
    return ((kh*WP + kw) << 7) + ((t & 1) << 6);
}

// ---------------- Phase 2: ring-buffered 2-chunk-phase implicit GEMM ------
// Grid: 28 pixel-tiles * nc batches. Block: 256 threads = 4 waves.
// Tile: 256 co x 112 px. 9 phases of 2 K-chunks; ONE barrier per phase.
// B: LDS ring of 3 phase-buffers (3 x 14336 B). Phase p reads ring[p%3];
//    stage(p+1) (issued pre-barrier) writes ring[(p+1)%3] - distinct from
//    ring[p%3] and ring[(p-1)%3] (mod-3), so no WAR race with one barrier.
// vmcnt(12): younger-than-stage(p) = A(p-1)x8 + stage(p+1)x4 = 12; in-order
//    vmcnt retirement guarantees own stage(p) landed; barrier propagates.
// A: fragment-ordered w8f -> a[8] regs (2 chunks), loaded pre-barrier,
//    dead after each phase's MFMAs (no double-buffer copy needed).
__launch_bounds__(256, 2)
__global__ void conv_kernel(const unsigned char* __restrict__ w8f,
                            const unsigned char* __restrict__ xp8,
                            const int* __restrict__ bias,
                            const float* __restrict__ wscale,
                            int* __restrict__ out,
                            int n0) {
    __shared__ __align__(16) unsigned char ldsB[3*PHB];

    int bx = blockIdx.x;
    int pt = bx % NPT;
    int nl = bx / NPT;
    int nb = n0 + nl;
    int p0 = pt * BN;

    int tid  = threadIdx.x;
    int lane = tid & 63;
    int wm   = tid >> 6;           // 0..3
    int lr   = lane & 15;
    int lg   = lane >> 4;

    // ---- B staging: slots s0,s1 per wave (16 px x 64B each) ----
    int l4 = lane >> 2;                              // row within 16-row group
    int sw = (lane & 3) ^ ((lane >> 3) & 3);         // swizzled data k-slot
    int s0 = wm*2;
    int s1 = (wm*2+1 > 6) ? 6 : wm*2+1;              // wave3 duplicates slot 6
    int s0u = __builtin_amdgcn_readfirstlane(s0);
    int s1u = __builtin_amdgcn_readfirstlane(s1);
    int pA = p0 + s0*16 + l4;
    int pB = p0 + s1*16 + l4;
    const unsigned char* bsrc0 =
        xp8 + ((size_t)((nl*HP + pA/WW)*WP + pA%WW))*CIN + sw*16;
    const unsigned char* bsrc1 =
        xp8 + ((size_t)((nl*HP + pB/WW)*WP + pB%WW))*CIN + sw*16;

    // ---- B fragment read address (swizzled) ----
    int rslot = lg ^ ((lr >> 1) & 3);
    int vb = lr*64 + rslot*16;                       // b[j] at vb + j*1024

    // ---- A fragment base: contiguous 1KB per (chunk, frag) ----
    const unsigned char* abase = w8f + (size_t)(wm*4)*1024 + (lr*64 + lg*16);

    v4i acc[4][NJ];
#pragma unroll
    for (int i = 0; i < 4; ++i)
#pragma unroll
        for (int j = 0; j < NJ; ++j)
            acc[i][j] = (v4i){0, 0, 0, 0};

#define STAGE2(P, ROFF) do {                                                   \
        int k0_ = koff_of(2*(P));                                              \
        int k1_ = koff_of(2*(P)+1);                                            \
        GLOAD_LDS(bsrc0 + k0_, &ldsB[(ROFF) + s0u*1024]);                      \
        GLOAD_LDS(bsrc1 + k0_, &ldsB[(ROFF) + s1u*1024]);                      \
        GLOAD_LDS(bsrc0 + k1_, &ldsB[(ROFF) + CHB + s0u*1024]);                \
        GLOAD_LDS(bsrc1 + k1_, &ldsB[(ROFF) + CHB + s1u*1024]);                \
    } while (0)

    // prologue: stage phase 0 into ring slot 0
    STAGE2(0, 0);

#pragma unroll
    for (int p = 0; p < NPHASE; ++p) {
        if (p < NPHASE-1) STAGE2(p+1, ((p+1)%3)*PHB);

        v4i a_[8];
#pragma unroll
        for (int i = 0; i < 4; ++i) {
            a_[i]   = *(const v4i*)(abase + (size_t)(2*p)*16384   + i*1024);
            a_[4+i] = *(const v4i*)(abase + (size_t)(2*p+1)*16384 + i*1024);
        }

        asm volatile("s_waitcnt vmcnt(12)" ::: "memory");
        __builtin_amdgcn_sched_barrier(0);
        __builtin_amdgcn_s_barrier();      // all waves' phase-p B in LDS

        int roff = (p % 3) * PHB;
        v4i b_[NJ];
#pragma unroll
        for (int j = 0; j < NJ; ++j)
            b_[j] = *(const v4i*)&ldsB[roff + vb + j*1024];
#pragma unroll
        for (int i = 0; i < 4; ++i)
#pragma unroll
            for (int j = 0; j < NJ; ++j)
                acc[i][j] = __builtin_amdgcn_mfma_i32_16x16x64_i8(
                    a_[i], b_[j], acc[i][j], 0, 0, 0);
#pragma unroll
        for (int j = 0; j < NJ; ++j)
            b_[j] = *(const v4i*)&ldsB[roff + CHB + vb + j*1024];
#pragma unroll
        for (int i = 0; i < 4; ++i)
#pragma unroll
            for (int j = 0; j < NJ; ++j)
                acc[i][j] = __builtin_amdgcn_mfma_i32_16x16x64_i8(
                    a_[4+i], b_[j], acc[i][j], 0, 0, 0);
        // no trailing barrier: ring-of-3 makes next stage target disjoint
    }
#undef STAGE2

    // Epilogue: q = clamp(rint((acc+bias) * (0.05*ws/0.1) + (-2)), -128, 127)
#pragma unroll
    for (int i = 0; i < 4; ++i) {
#pragma unroll
        for (int rr = 0; rr < 4; ++rr) {
            int co = wm*64 + i*16 + lg*4 + rr;
            float sc = __fdiv_rn(__fmul_rn(0.05f, wscale[co]), 0.1f);
            int bs = bias[co];
            int* orow = out + ((size_t)(nb*COUT + co))*PIX + p0;
#pragma unroll
            for (int j = 0; j < NJ; ++j) {
                float accf = (float)(acc[i][j][rr] + bs);
                float y = __fadd_rn(__fmul_rn(accf, sc), -2.0f);
                y = rintf(y);
                y = fminf(fmaxf(y, -128.0f), 127.0f);
                orow[j*16 + lr] = (int)y;
            }
        }
    }
}

// ---------------- Fallback: naive direct conv (only if ws too small) ------
__launch_bounds__(256)
__global__ void conv_direct_kernel(const int* __restrict__ x,
                                   const int* __restrict__ wt,
                                   const int* __restrict__ bias,
                                   const float* __restrict__ wscale,
                                   int* __restrict__ out) {
    size_t idx = (size_t)blockIdx.x * 256 + threadIdx.x;
    if (idx >= (size_t)NB * COUT * PIX) return;
    int w  = idx % WW;
    int h  = (idx / WW) % HH;
    int co = (idx / PIX) % COUT;
    int nb = idx / ((size_t)PIX * COUT);
    int acc = 0;
    for (int ci = 0; ci < CIN; ++ci) {
        const int* xb = x + ((size_t)(nb*CIN + ci)*HH)*WW;
        const int* wb = wt + ((size_t)(co*CIN + ci)*9);
        for (int kh = 0; kh < 3; ++kh) {
            int hh = h + kh - 1;
            for (int kw = 0; kw < 3; ++kw) {
                int ww2 = w + kw - 1;
                int xv = (hh >= 0 && hh < HH && ww2 >= 0 && ww2 < WW)
                         ? xb[hh*WW + ww2] : 3;
                acc += xv * wb[kh*3 + kw];
            }
        }
    }
    float sc = __fdiv_rn(__fmul_rn(0.05f, wscale[co]), 0.1f);
    float y = __fadd_rn(__fmul_rn((float)(acc + bias[co]), sc), -2.0f);
    y = rintf(y);
    y = fminf(fmaxf(y, -128.0f), 127.0f);
    out[idx] = (int)y;
}

extern "C" void kernel_launch(void* const* d_in, const int* in_sizes, int n_in,
                              void* d_out, int out_size, void* d_ws, size_t ws_size,
                              hipStream_t stream) {
    const int*   x      = (const int*)d_in[0];
    const int*   weight = (const int*)d_in[1];
    const int*   bias   = (const int*)d_in[2];
    const float* wscale = (const float*)d_in[3];
    int*         out    = (int*)d_out;

    const size_t XOFF = 320u << 10;                  // w8f region: 288KB used
    const size_t BPB  = (size_t)HP * WP * CIN;       // 430,592 B per batch

    int nchk = 0;
    if (ws_size >= XOFF + BPB) {
        size_t navail = (ws_size - XOFF) / BPB;
        nchk = navail >= 32 ? 32 : navail >= 16 ? 16 : navail >= 8 ? 8
             : navail >= 4 ? 4 : navail >= 2 ? 2 : 1;
    }

    if (nchk == 0) {
        size_t total = (size_t)NB * COUT * PIX;
        conv_direct_kernel<<<dim3((total + 255) / 256), dim3(256), 0, stream>>>(
            x, weight, bias, wscale, out);
        return;
    }

    unsigned char* ws  = (unsigned char*)d_ws;
    unsigned char* w8f = ws;
    unsigned char* xp8 = ws + XOFF;

    pack_w_kernel<<<dim3(COUT), dim3(128), 0, stream>>>(weight, w8f);
    for (int n0 = 0; n0 < NB; n0 += nchk) {
        int nc = (NB - n0 < nchk) ? (NB - n0) : nchk;
        pack_x_kernel<<<dim3(nc*HP), dim3(256), 0, stream>>>(x, xp8, n0);
        conv_kernel<<<dim3(NPT*nc), dim3(256), 0, stream>>>(w8f, xp8, bias, wscale, out, n0);
    }
}